// Round 1
// 843.373 us; speedup vs baseline: 1.1010x; 1.1010x over previous
//
#include <hip/hip_runtime.h>

typedef __bf16 bf16x8 __attribute__((ext_vector_type(8)));
typedef unsigned short u16x8 __attribute__((ext_vector_type(8)));
typedef float f32x4 __attribute__((ext_vector_type(4)));

#define S_DIM 2048
#define D_DIM 128
#define N1 67108864LL   // 16*2048*2048 elements of x1[0]
#define N2 4194304LL    // 16*2048*128  elements of x2[0]
#define RANK1 66437774u // 0-based: k-1, k = int(N1*0.99)
#define RANK2 4152359u  // 0-based: k-1, k = int(N2*0.99)

#define OUT_O1 8388608
#define OUT_O2 8388609
#define OUT_COLS 8388610
#define OUT_SCALE 8388635

// ws layout (u32 indices)
#define WS_H0 0        // 2048: x1 approx hist (now filled by fused GEMM)
#define WS_H1 2048     // 2048: x2 radix pass1
#define WS_H2 4096     // 2048: x2 radix pass2
#define WS_H3 6144     // 512 : x2 radix pass3
#define WS_STATE 6656  // [0]=rank [1]=b1 [2]=b2 [3]=result bits
#define WS_SMAX 6660   // scale max (float bits)
#define WS_MASK 6664   // 4 u32: selected-column bitmask
#define WS_SUMSQ 6672  // 128 floats: column sum of squares
#define WS_TOTAL 8192

__device__ __forceinline__ unsigned short f2bf(float f) {
  unsigned u = __float_as_uint(f);
  return (unsigned short)((u + 0x7FFFu + ((u >> 16) & 1u)) >> 16); // RNE
}

__device__ __forceinline__ unsigned long long pack4(float x, float y, float z, float w) {
  return (unsigned long long)f2bf(x)
       | ((unsigned long long)f2bf(y) << 16)
       | ((unsigned long long)f2bf(z) << 32)
       | ((unsigned long long)f2bf(w) << 48);
}

// ---------------------------------------------------------------- init
__global__ void init_ws(unsigned* __restrict__ ws) {
  int i = blockIdx.x * 256 + threadIdx.x;
  // NOTE: single store per location — a separate `if (i==0) ws[WS_STATE]=RANK2`
  // raced with the i==WS_STATE thread's zero-store (round-1 failure).
  if (i < WS_TOTAL) ws[i] = (i == WS_STATE) ? RANK2 : 0u;
}

// ---------------------------------------------------------------- GEMM (+ fused x1[0] histogram)
// per (b,h): C(2048x128) = A(2048x2048) * B(2048x128), bf16 MFMA, f32 acc.
// grid 512 = 32 bh * 16 m-tiles; block 256 = 4 waves (2x2 over 128x128 tile).
// Pipeline: reg-stage tile k+1's global loads before the barrier so HBM
// latency hides under tile k's ds_read+MFMA (T14 issue-early/write-late).
// x1[0] histogram fused: each A element passes through exactly one thread's
// registers exactly once; per-wave private LDS sub-hist, global flush at end.
#define LDA 40  // 32 + 8 pad (keeps 16B alignment, breaks pow2 bank stride)

__global__ __launch_bounds__(256, 2) void gemm_kernel(
    const float* __restrict__ x1, const float* __restrict__ x2,
    float* __restrict__ out, unsigned* __restrict__ hist) {
  __shared__ __align__(16) unsigned short lA[128 * LDA];
  __shared__ __align__(16) unsigned short lB[128 * LDA];
  __shared__ unsigned lh[4][2048];  // per-wave sub-hist (no cross-wave atomics)

  // XCD swizzle: blocks sharing a B panel (same bh) keep the same blockIdx%8
  // so they land on one XCD's L2 (dispatch round-robin heuristic — perf only).
  const int bid = blockIdx.x;
  const int bh = (bid & 7) + ((bid >> 7) << 3);  // bid%8 + 8*(bid/128)
  const int mt = (bid >> 3) & 15;
  const int t = threadIdx.x;
  const int lane = t & 63;
  const int wave = t >> 6;
  const int wm = (wave >> 1) * 64;
  const int wn = (wave & 1) * 64;
  const int l15 = lane & 15;
  const int quad = lane >> 4;
  const bool do_hist = (bh < 16);  // b==0 half of x1

  unsigned* myh = lh[wave];
  if (do_hist) {
    // wave-private init: each wave zeroes only its OWN sub-hist, so no barrier
    // is needed before the first iteration's atomics (wave program order).
    for (int i = lane; i < 2048; i += 64) myh[i] = 0u;
  }

  const float* Ag = x1 + (long long)bh * S_DIM * S_DIM + (long long)mt * 128 * S_DIM;
  const float* Bg = x2 + (long long)bh * S_DIM * D_DIM;
  float* Cg = out + (long long)bh * S_DIM * D_DIM + (long long)mt * 128 * D_DIM;

  f32x4 acc[4][4];
#pragma unroll
  for (int i = 0; i < 4; ++i)
#pragma unroll
    for (int j = 0; j < 4; ++j) acc[i][j] = f32x4{0.f, 0.f, 0.f, 0.f};

  const int a_seg = t & 7;   // 8 segs of 4 floats over K=32
  const int a_row = t >> 3;  // 0..31
  const int b_n = t & 127;   // column of B
  const int b_kq = t >> 7;   // 0..1 (k half)

  // prologue: load tile kb=0 into registers
  float4 a_r[4];
  float4 b_r[4];
#pragma unroll
  for (int p = 0; p < 4; ++p)
    a_r[p] = *reinterpret_cast<const float4*>(Ag + (long long)(a_row + p * 32) * S_DIM + a_seg * 4);
#pragma unroll
  for (int g = 0; g < 4; ++g) {
    int k0 = b_kq * 16 + g * 4;
    long long base = (long long)k0 * D_DIM + b_n;
    b_r[g].x = Bg[base];
    b_r[g].y = Bg[base + D_DIM];
    b_r[g].z = Bg[base + 2 * D_DIM];
    b_r[g].w = Bg[base + 3 * D_DIM];
  }

  for (int kb = 0; kb < S_DIM; kb += 32) {
    // convert + ds_write current tile (consumes a_r/b_r values)
#pragma unroll
    for (int p = 0; p < 4; ++p) {
      int row = a_row + p * 32;
      *reinterpret_cast<unsigned long long*>(&lA[row * LDA + a_seg * 4]) =
          pack4(a_r[p].x, a_r[p].y, a_r[p].z, a_r[p].w);
    }
#pragma unroll
    for (int g = 0; g < 4; ++g) {
      int k0 = b_kq * 16 + g * 4;
      *reinterpret_cast<unsigned long long*>(&lB[b_n * LDA + k0]) =
          pack4(b_r[g].x, b_r[g].y, b_r[g].z, b_r[g].w);
    }

    // fused histogram on the exact f32 bits (wave-private region)
    if (do_hist) {
#pragma unroll
      for (int p = 0; p < 4; ++p) {
        atomicAdd(&myh[__float_as_uint(a_r[p].x) >> 19], 1u);
        atomicAdd(&myh[__float_as_uint(a_r[p].y) >> 19], 1u);
        atomicAdd(&myh[__float_as_uint(a_r[p].z) >> 19], 1u);
        atomicAdd(&myh[__float_as_uint(a_r[p].w) >> 19], 1u);
      }
    }

    // issue next tile's global loads NOW — they fly during ds_read+MFMA
    if (kb + 32 < S_DIM) {
#pragma unroll
      for (int p = 0; p < 4; ++p)
        a_r[p] = *reinterpret_cast<const float4*>(
            Ag + (long long)(a_row + p * 32) * S_DIM + (kb + 32) + a_seg * 4);
#pragma unroll
      for (int g = 0; g < 4; ++g) {
        int k0 = b_kq * 16 + g * 4;
        long long base = (long long)(kb + 32 + k0) * D_DIM + b_n;
        b_r[g].x = Bg[base];
        b_r[g].y = Bg[base + D_DIM];
        b_r[g].z = Bg[base + 2 * D_DIM];
        b_r[g].w = Bg[base + 3 * D_DIM];
      }
    }
    __syncthreads();

    bf16x8 af[4], bfr[4];
#pragma unroll
    for (int i = 0; i < 4; ++i) {
      af[i] = __builtin_bit_cast(bf16x8,
          *reinterpret_cast<const u16x8*>(&lA[(wm + i * 16 + l15) * LDA + quad * 8]));
      bfr[i] = __builtin_bit_cast(bf16x8,
          *reinterpret_cast<const u16x8*>(&lB[(wn + i * 16 + l15) * LDA + quad * 8]));
    }
#pragma unroll
    for (int i = 0; i < 4; ++i)
#pragma unroll
      for (int j = 0; j < 4; ++j)
        acc[i][j] = __builtin_amdgcn_mfma_f32_16x16x32_bf16(af[i], bfr[j], acc[i][j], 0, 0, 0);
    __syncthreads();  // protect lA/lB before next iteration's ds_write
  }

  // epilogue: C/D layout col=lane&15, row=quad*4+reg
#pragma unroll
  for (int i = 0; i < 4; ++i) {
#pragma unroll
    for (int j = 0; j < 4; ++j) {
      int row0 = wm + i * 16 + quad * 4;
      int col = wn + j * 16 + l15;
#pragma unroll
      for (int r = 0; r < 4; ++r)
        Cg[(long long)(row0 + r) * D_DIM + col] = acc[i][j][r];
    }
  }

  // hist flush (last loop barrier already synchronized all waves' atomics)
  if (do_hist) {
    for (int i = t; i < 2048; i += 256) {
      unsigned s = lh[0][i] + lh[1][i] + lh[2][i] + lh[3][i];
      if (s) atomicAdd(&hist[i], s);
    }
  }
}

// ---------------------------------------------------------------- x1 quantile select (hist produced by gemm)
__global__ void x1_select(const unsigned* __restrict__ hist, float* __restrict__ out) {
  __shared__ unsigned ps[256];
  const int t = threadIdx.x;
  unsigned v[8];
  unsigned s = 0;
#pragma unroll
  for (int j = 0; j < 8; ++j) { v[j] = hist[t * 8 + j]; s += v[j]; }
  ps[t] = s;
  __syncthreads();
  for (int off = 1; off < 256; off <<= 1) {
    unsigned add = (t >= off) ? ps[t - off] : 0u;
    __syncthreads();
    ps[t] += add;
    __syncthreads();
  }
  unsigned incl = ps[t];
  unsigned before = incl - s;
  if (RANK1 >= before && RANK1 < incl) {
    unsigned rr = RANK1 - before;
    for (int j = 0; j < 8; ++j) {
      if (rr < v[j]) {
        unsigned b = (unsigned)(t * 8 + j);
        float lo = __uint_as_float(b << 19);
        float hi = __uint_as_float((b + 1u) << 19);
        out[OUT_O1] = lo + (hi - lo) * (((float)rr + 0.5f) / (float)v[j]);
        break;
      }
      rr -= v[j];
    }
  }
}

// ---------------------------------------------------------------- x2 exact radix select (abs bits: 11+11+9)
__global__ void x2_hist(const float* __restrict__ x2, unsigned* __restrict__ h,
                        const unsigned* __restrict__ state, int phase) {
  __shared__ unsigned lh[2048];
  const int nb = (phase == 3) ? 512 : 2048;
  for (int i = threadIdx.x; i < nb; i += 256) lh[i] = 0u;
  __syncthreads();
  const unsigned b1 = state[1];
  const unsigned pfx2 = (state[1] << 11) | state[2];
  long long i0 = (long long)(blockIdx.x * 256 + threadIdx.x) * 4;
  long long stride = (long long)gridDim.x * 1024;
  for (long long i = i0; i < N2; i += stride) {
    float4 v = *reinterpret_cast<const float4*>(x2 + i);
    float fv[4] = {v.x, v.y, v.z, v.w};
#pragma unroll
    for (int j = 0; j < 4; ++j) {
      unsigned key = __float_as_uint(fv[j]) & 0x7FFFFFFFu;
      if (phase == 1) {
        atomicAdd(&lh[key >> 20], 1u);
      } else if (phase == 2) {
        if ((key >> 20) == b1) atomicAdd(&lh[(key >> 9) & 0x7FFu], 1u);
      } else {
        if ((key >> 9) == pfx2) atomicAdd(&lh[key & 0x1FFu], 1u);
      }
    }
  }
  __syncthreads();
  for (int i = threadIdx.x; i < nb; i += 256)
    if (lh[i]) atomicAdd(&h[i], lh[i]);
}

__global__ void x2_scan(const unsigned* __restrict__ h, unsigned* state,
                        float* __restrict__ out, int phase) {
  __shared__ unsigned ps[256];
  const int nb = (phase == 3) ? 512 : 2048;
  const int per = nb >> 8;
  const int t = threadIdx.x;
  const unsigned r = state[0];   // read BEFORE barriers (winner writes after)
  const unsigned sb1 = state[1];
  const unsigned sb2 = state[2];
  unsigned v[8];
  unsigned s = 0;
  for (int j = 0; j < per; ++j) { v[j] = h[t * per + j]; s += v[j]; }
  ps[t] = s;
  __syncthreads();
  for (int off = 1; off < 256; off <<= 1) {
    unsigned add = (t >= off) ? ps[t - off] : 0u;
    __syncthreads();
    ps[t] += add;
    __syncthreads();
  }
  unsigned incl = ps[t];
  unsigned before = incl - s;
  if (r >= before && r < incl) {
    unsigned rr = r - before;
    for (int j = 0; j < per; ++j) {
      if (rr < v[j]) {
        unsigned b = (unsigned)(t * per + j);
        state[0] = rr;
        if (phase == 1) state[1] = b;
        else if (phase == 2) state[2] = b;
        else {
          unsigned bits = (sb1 << 20) | (sb2 << 9) | b;
          state[3] = bits;
          out[OUT_O2] = __uint_as_float(bits);
        }
        break;
      }
      rr -= v[j];
    }
  }
}

// ---------------------------------------------------------------- column norms of residual
__global__ void colnorm_kernel(const float* __restrict__ x2,
                               const unsigned* __restrict__ state,
                               float* __restrict__ sumsq) {
  const float thr = __uint_as_float(state[3]);
  const int t = threadIdx.x;
  const int c = t & 127;
  const int half = t >> 7;
  float local = 0.f;
  for (int i = 0; i < 64; ++i) {
    int row = blockIdx.x * 128 + i * 2 + half;
    float x = x2[(long long)row * 128 + c];
    if (fabsf(x) <= thr) local += x * x;  // keep |x| <= outliner (ref zeroes strictly >)
  }
  __shared__ float red[256];
  red[t] = local;
  __syncthreads();
  if (half == 0) atomicAdd(&sumsq[c], red[c] + red[c + 128]);
}

// top-25 descending, tie -> lower index (jax.lax.top_k semantics)
__global__ void topk_kernel(const float* __restrict__ sumsq, float* __restrict__ out,
                            unsigned* __restrict__ mask) {
  __shared__ float v[128];
  __shared__ float rv[128];
  __shared__ int ri[128];
  __shared__ unsigned msk[4];
  const int t = threadIdx.x;  // 128 threads
  v[t] = sumsq[t];
  if (t < 4) msk[t] = 0u;
  __syncthreads();
  for (int s = 0; s < 25; ++s) {
    rv[t] = v[t];
    ri[t] = t;
    __syncthreads();
    for (int off = 64; off >= 1; off >>= 1) {
      if (t < off) {
        float a = rv[t], b = rv[t + off];
        int ia = ri[t], ib = ri[t + off];
        if (b > a || (b == a && ib < ia)) { rv[t] = b; ri[t] = ib; }
      }
      __syncthreads();
    }
    if (t == 0) {
      int c = ri[0];
      out[OUT_COLS + s] = (float)c;
      v[c] = -1.0f;
      msk[c >> 5] |= 1u << (c & 31);
    }
    __syncthreads();
  }
  if (t < 4) mask[t] = msk[t];
}

// max |resid| over selected columns
__global__ void scale_kernel(const float* __restrict__ x2,
                             const unsigned* __restrict__ state,
                             const unsigned* __restrict__ mask,
                             unsigned* __restrict__ smax) {
  const float thr = __uint_as_float(state[3]);
  unsigned long long mlo = (unsigned long long)mask[0] | ((unsigned long long)mask[1] << 32);
  unsigned long long mhi = (unsigned long long)mask[2] | ((unsigned long long)mask[3] << 32);
  long long i0 = (long long)(blockIdx.x * 256 + threadIdx.x) * 4;
  long long stride = (long long)gridDim.x * 1024;
  float best = 0.f;
  for (long long i = i0; i < N2; i += stride) {
    float4 v = *reinterpret_cast<const float4*>(x2 + i);
    float fv[4] = {v.x, v.y, v.z, v.w};
    int cbase = (int)(i & 127);
#pragma unroll
    for (int j = 0; j < 4; ++j) {
      int c = cbase + j;
      unsigned long long w = (c < 64) ? mlo : mhi;
      if ((w >> (c & 63)) & 1ULL) {
        float a = fabsf(fv[j]);
        if (a <= thr && a > best) best = a;
      }
    }
  }
  __shared__ float red[256];
  red[threadIdx.x] = best;
  __syncthreads();
  for (int off = 128; off >= 1; off >>= 1) {
    if (threadIdx.x < off) red[threadIdx.x] = fmaxf(red[threadIdx.x], red[threadIdx.x + off]);
    __syncthreads();
  }
  if (threadIdx.x == 0) atomicMax(smax, __float_as_uint(red[0]));
}

__global__ void finalize_kernel(const unsigned* __restrict__ smax, float* __restrict__ out) {
  out[OUT_SCALE] = __uint_as_float(*smax) / 127.0f;
}

// ---------------------------------------------------------------- launch
extern "C" void kernel_launch(void* const* d_in, const int* in_sizes, int n_in,
                              void* d_out, int out_size, void* d_ws, size_t ws_size,
                              hipStream_t stream) {
  (void)in_sizes; (void)n_in; (void)out_size; (void)ws_size;
  const float* x1 = (const float*)d_in[0];
  const float* x2 = (const float*)d_in[1];
  float* out = (float*)d_out;
  unsigned* ws = (unsigned*)d_ws;

  init_ws<<<32, 256, 0, stream>>>(ws);
  gemm_kernel<<<512, 256, 0, stream>>>(x1, x2, out, ws + WS_H0);  // fused x1 hist
  x1_select<<<1, 256, 0, stream>>>(ws + WS_H0, out);
  x2_hist<<<256, 256, 0, stream>>>(x2, ws + WS_H1, ws + WS_STATE, 1);
  x2_scan<<<1, 256, 0, stream>>>(ws + WS_H1, ws + WS_STATE, out, 1);
  x2_hist<<<256, 256, 0, stream>>>(x2, ws + WS_H2, ws + WS_STATE, 2);
  x2_scan<<<1, 256, 0, stream>>>(ws + WS_H2, ws + WS_STATE, out, 2);
  x2_hist<<<256, 256, 0, stream>>>(x2, ws + WS_H3, ws + WS_STATE, 3);
  x2_scan<<<1, 256, 0, stream>>>(ws + WS_H3, ws + WS_STATE, out, 3);
  colnorm_kernel<<<256, 256, 0, stream>>>(x2, ws + WS_STATE, (float*)(ws + WS_SUMSQ));
  topk_kernel<<<1, 128, 0, stream>>>((const float*)(ws + WS_SUMSQ), out, ws + WS_MASK);
  scale_kernel<<<256, 256, 0, stream>>>(x2, ws + WS_STATE, ws + WS_MASK, ws + WS_SMAX);
  finalize_kernel<<<1, 1, 0, stream>>>(ws + WS_SMAX, out);
}